// Round 1
// baseline (3090.103 us; speedup 1.0000x reference)
//
#include <hip/hip_runtime.h>
#include <hip/hip_bf16.h>
#include <cstdint>
#include <cstddef>

#define T_TOK 1024
#define H_DIM 2048
#define NH 32
#define HS 64
#define TH (T_TOK * H_DIM)
#define HH (H_DIM * H_DIM)

using short8 = __attribute__((ext_vector_type(8))) short;
using f32x4  = __attribute__((ext_vector_type(4))) float;
typedef __hip_bfloat16 bf16;

__device__ __forceinline__ float sigmoidf_(float x) { return 1.0f / (1.0f + expf(-x)); }

__device__ __forceinline__ float wsum64(float v) {
#pragma unroll
    for (int m = 32; m; m >>= 1) v += __shfl_xor(v, m, 64);
    return v;
}

// ---------------- cast big weights fp32 -> bf16 ----------------
struct CastPar { const float* src[4]; bf16* dst[4]; };
__global__ __launch_bounds__(256) void castw_kernel(CastPar p) {
    int z = blockIdx.z;
    const float4* s = (const float4*)p.src[z];
    bf16* d = p.dst[z];
    int i = blockIdx.x * 256 + threadIdx.x;   // float4 index, HH/4 total
    float4 v = s[i];
    int b = i * 4;
    d[b + 0] = __float2bfloat16(v.x);
    d[b + 1] = __float2bfloat16(v.y);
    d[b + 2] = __float2bfloat16(v.z);
    d[b + 3] = __float2bfloat16(v.w);
}

// ---------------- transpose + cast small weights ----------------
struct TPar { const float* src[8]; bf16* dst[8]; int R[8]; int C[8]; };
__global__ __launch_bounds__(256) void transpose_kernel(TPar p) {
    int z = blockIdx.z;
    int R = p.R[z], C = p.C[z];
    int e = blockIdx.x * 256 + threadIdx.x;
    if (e >= R * C) return;
    int r = e / C, c = e % C;
    p.dst[z][(size_t)c * R + r] = __float2bfloat16(p.src[z][e]);
}

// ---------------- LayerNorm (ln1) over H, write xn + state1_out ----------------
__global__ __launch_bounds__(256) void ln_kernel(const float* __restrict__ x,
                                                 const float* __restrict__ w,
                                                 const float* __restrict__ b,
                                                 float* __restrict__ xn,
                                                 float* __restrict__ s1out) {
    int t = blockIdx.x, tid = threadIdx.x;
    const float* xt = x + (size_t)t * H_DIM;
    float v[8]; float s = 0.f, s2 = 0.f;
#pragma unroll
    for (int e = 0; e < 8; e++) { v[e] = xt[tid + 256 * e]; s += v[e]; s2 += v[e] * v[e]; }
    s = wsum64(s); s2 = wsum64(s2);
    __shared__ float ls[8];
    int wid = tid >> 6, ln = tid & 63;
    if (ln == 0) { ls[wid] = s; ls[4 + wid] = s2; }
    __syncthreads();
    s = ls[0] + ls[1] + ls[2] + ls[3];
    s2 = ls[4] + ls[5] + ls[6] + ls[7];
    float mu = s * (1.f / H_DIM);
    float var = s2 * (1.f / H_DIM) - mu * mu;
    float inv = rsqrtf(var + 1e-5f);
#pragma unroll
    for (int e = 0; e < 8; e++) {
        int h = tid + 256 * e;
        float o = (v[e] - mu) * inv * w[h] + b[h];
        xn[(size_t)t * H_DIM + h] = o;
        if (t == T_TOK - 1) s1out[h] = o;
    }
}

// ---------------- token-shift mixes -> 6 bf16 buffers ----------------
struct MixPar { const float* xn; const float* state1; const float* mv[6]; bf16* out[6]; };
__global__ __launch_bounds__(256) void mix_kernel(MixPar p) {
    int t = blockIdx.x, tid = threadIdx.x;
#pragma unroll
    for (int e = 0; e < 8; e++) {
        int h = tid + 256 * e;
        size_t idx = (size_t)t * H_DIM + h;
        float cur = p.xn[idx];
        float prev = (t == 0) ? p.state1[h] : p.xn[idx - H_DIM];
        float sx = prev - cur;
#pragma unroll
        for (int q = 0; q < 6; q++)
            p.out[q][idx] = __float2bfloat16(cur + p.mv[q][h] * sx);
    }
}

// ---------------- MFMA bf16 GEMM: C[M,N] = X[M,K] @ W[N,K]^T ----------------
#define BM 128
#define BN 128
#define BK 32
#define LDK 40   // +8 bf16 pad to break power-of-2 bank stride

__device__ __forceinline__ void gemm_core(const bf16* __restrict__ X, const bf16* __restrict__ W,
                                          int M, int N, int K, int act,
                                          const float* __restrict__ bias,
                                          const float* __restrict__ resid,
                                          float* __restrict__ outF, bf16* __restrict__ outB) {
    __shared__ short As[BM * LDK];
    __shared__ short Bs[BN * LDK];
    int m0 = blockIdx.y * BM, n0 = blockIdx.x * BN;
    if (n0 >= N) return;
    int tid = threadIdx.x;
    int lane = tid & 63, wid = tid >> 6;
    int m_off = (wid >> 1) * 64, n_off = (wid & 1) * 64;
    int lr = lane & 15, lq = lane >> 4;

    f32x4 acc[4][4];
#pragma unroll
    for (int a = 0; a < 4; a++)
#pragma unroll
        for (int b = 0; b < 4; b++)
#pragma unroll
            for (int r = 0; r < 4; r++) acc[a][b][r] = 0.f;

    for (int k0 = 0; k0 < K; k0 += BK) {
#pragma unroll
        for (int it = 0; it < 2; it++) {
            int c = tid + it * 256;
            int r = c >> 2;
            int cc = (c & 3) * 8;
            uint4 va = *(const uint4*)(X + (size_t)(m0 + r) * K + k0 + cc);
            *(uint4*)&As[r * LDK + cc] = va;
            uint4 vb;
            if (n0 + r < N) vb = *(const uint4*)(W + (size_t)(n0 + r) * K + k0 + cc);
            else            vb = make_uint4(0u, 0u, 0u, 0u);
            *(uint4*)&Bs[r * LDK + cc] = vb;
        }
        __syncthreads();
        short8 af[4], bfr[4];
#pragma unroll
        for (int mi = 0; mi < 4; mi++)
            af[mi] = *(const short8*)&As[(m_off + mi * 16 + lr) * LDK + lq * 8];
#pragma unroll
        for (int ni = 0; ni < 4; ni++)
            bfr[ni] = *(const short8*)&Bs[(n_off + ni * 16 + lr) * LDK + lq * 8];
#pragma unroll
        for (int mi = 0; mi < 4; mi++)
#pragma unroll
            for (int ni = 0; ni < 4; ni++)
                acc[mi][ni] = __builtin_amdgcn_mfma_f32_16x16x32_bf16(af[mi], bfr[ni], acc[mi][ni], 0, 0, 0);
        __syncthreads();
    }
    // epilogue: D row = quad*4+reg, col = lane&15  (m89-verified layout)
#pragma unroll
    for (int mi = 0; mi < 4; mi++)
#pragma unroll
        for (int ni = 0; ni < 4; ni++)
#pragma unroll
            for (int r = 0; r < 4; r++) {
                int rowg = m0 + m_off + mi * 16 + lq * 4 + r;
                int colg = n0 + n_off + ni * 16 + lr;
                if (colg < N) {
                    float v = acc[mi][ni][r];
                    if (bias) v += bias[colg];
                    if (act == 1) v = sigmoidf_(v);
                    else if (act == 2) v = tanhf(v);
                    size_t o = (size_t)rowg * N + colg;
                    if (resid) v += resid[o];
                    if (outF) outF[o] = v;
                    else      outB[o] = __float2bfloat16(v);
                }
            }
}

struct GPar {
    const bf16* X[4]; const bf16* W[4];
    float* outF[4]; bf16* outB[4];
    const float* bias[4]; const float* resid[4];
    int N[4]; int K[4]; int act[4]; int M;
};
__global__ __launch_bounds__(256) void gemm_z_kernel(GPar p) {
    int z = blockIdx.z;
    gemm_core(p.X[z], p.W[z], p.M, p.N[z], p.K[z], p.act[z], p.bias[z], p.resid[z], p.outF[z], p.outB[z]);
}

// ---------------- elementwise prep for the scan ----------------
__global__ __launch_bounds__(64) void prep_kernel(float* __restrict__ k_io, float* __restrict__ v_io,
                                                  const float* __restrict__ v_first,
                                                  const float* __restrict__ vres,
                                                  float* __restrict__ w_io, float* __restrict__ a_io,
                                                  float* __restrict__ as_out,
                                                  const float* __restrict__ k_k,
                                                  const float* __restrict__ k_a,
                                                  const float* __restrict__ w0) {
    int h = blockIdx.x, t = blockIdx.y, i = threadIdx.x;
    int hi = h * HS + i;
    size_t idx = (size_t)t * H_DIM + hi;
    float kf = k_io[idx];
    float kk = kf * k_k[hi];
    float ss = wsum64(kk * kk);
    float kkn = kk / (sqrtf(ss) + 1e-12f);
    float a = a_io[idx];
    k_io[idx] = kf * (1.f + (a - 1.f) * k_a[hi]);
    float vv = v_io[idx];
    v_io[idx] = vv + (v_first[idx] - vv) * vres[idx];
    w_io[idx] = expf(-0.606531f * sigmoidf_(w0[hi] + w_io[idx]));
    a_io[idx] = kkn * a;     // b_seq
    as_out[idx] = -kkn;      // a_seq
}

// ---------------- sequential WKV7 scan: one wave per head ----------------
// lane i owns state row S[i][0..63] in registers; j-vectors come in via
// uniform (scalar) loads so both reductions are lane-local.
__global__ __launch_bounds__(64) void scan_kernel(const float* __restrict__ w_s,
                                                  const float* __restrict__ k_s,
                                                  const float* __restrict__ v_s,
                                                  const float* __restrict__ as_s,
                                                  const float* __restrict__ b_s,
                                                  const float* __restrict__ r_s,
                                                  const float* __restrict__ s2in,
                                                  float* __restrict__ y,
                                                  float* __restrict__ s2out) {
    int h = blockIdx.x, i = threadIdx.x;
    float S[HS];
    const float4* sp = (const float4*)(s2in + (size_t)h * HS * HS + (size_t)i * HS);
#pragma unroll
    for (int j = 0; j < HS / 4; j++) {
        float4 t4 = sp[j];
        S[4 * j] = t4.x; S[4 * j + 1] = t4.y; S[4 * j + 2] = t4.z; S[4 * j + 3] = t4.w;
    }
    for (int t = 0; t < T_TOK; t++) {
        size_t base = (size_t)t * H_DIM + h * HS;
        const float* wv = w_s + base;
        const float* av = as_s + base;
        const float* bv = b_s + base;
        const float* kv = k_s + base;
        const float* rv = r_s + base;
        float vi = v_s[base + i];
        float sa0 = 0, sa1 = 0, sa2 = 0, sa3 = 0;
#pragma unroll
        for (int j = 0; j < HS; j += 4) {
            S[j]     *= wv[j];     sa0 = fmaf(S[j],     av[j],     sa0);
            S[j + 1] *= wv[j + 1]; sa1 = fmaf(S[j + 1], av[j + 1], sa1);
            S[j + 2] *= wv[j + 2]; sa2 = fmaf(S[j + 2], av[j + 2], sa2);
            S[j + 3] *= wv[j + 3]; sa3 = fmaf(S[j + 3], av[j + 3], sa3);
        }
        float sa = (sa0 + sa1) + (sa2 + sa3);
        float o0 = 0, o1 = 0, o2 = 0, o3 = 0;
#pragma unroll
        for (int j = 0; j < HS; j += 4) {
            S[j]     = fmaf(sa, bv[j],     fmaf(vi, kv[j],     S[j]));     o0 = fmaf(S[j],     rv[j],     o0);
            S[j + 1] = fmaf(sa, bv[j + 1], fmaf(vi, kv[j + 1], S[j + 1])); o1 = fmaf(S[j + 1], rv[j + 1], o1);
            S[j + 2] = fmaf(sa, bv[j + 2], fmaf(vi, kv[j + 2], S[j + 2])); o2 = fmaf(S[j + 2], rv[j + 2], o2);
            S[j + 3] = fmaf(sa, bv[j + 3], fmaf(vi, kv[j + 3], S[j + 3])); o3 = fmaf(S[j + 3], rv[j + 3], o3);
        }
        y[base + i] = (o0 + o1) + (o2 + o3);
    }
    float4* so = (float4*)(s2out + (size_t)h * HS * HS + (size_t)i * HS);
#pragma unroll
    for (int j = 0; j < HS / 4; j++) {
        float4 t4;
        t4.x = S[4 * j]; t4.y = S[4 * j + 1]; t4.z = S[4 * j + 2]; t4.w = S[4 * j + 3];
        so[j] = t4;
    }
}

// ---------------- groupnorm + bonus + gate -> bf16 for final GEMM ----------------
__global__ __launch_bounds__(64) void post_kernel(const float* __restrict__ y,
                                                  const float* __restrict__ r_s,
                                                  const float* __restrict__ k_s,
                                                  const float* __restrict__ v_s,
                                                  const float* __restrict__ g_s,
                                                  const float* __restrict__ r_k,
                                                  const float* __restrict__ lnw,
                                                  const float* __restrict__ lnb,
                                                  bf16* __restrict__ ybig) {
    int h = blockIdx.x, t = blockIdx.y, i = threadIdx.x;
    int hi = h * HS + i;
    size_t idx = (size_t)t * H_DIM + hi;
    float yv = y[idx];
    float mu = wsum64(yv) * (1.f / HS);
    float d = yv - mu;
    float var = wsum64(d * d) * (1.f / HS);
    float yn = d * rsqrtf(var + 0.00064f);
    float bd = wsum64(r_s[idx] * k_s[idx] * r_k[hi]);
    float val = (yn * lnw[hi] + lnb[hi] + bd * v_s[idx]) * g_s[idx];
    ybig[idx] = __float2bfloat16(val);
}

// ---------------- launcher ----------------
extern "C" void kernel_launch(void* const* d_in, const int* in_sizes, int n_in,
                              void* d_out, int out_size, void* d_ws, size_t ws_size,
                              hipStream_t stream) {
    const float* x      = (const float*)d_in[0];
    const float* state1 = (const float*)d_in[1];
    const float* state2 = (const float*)d_in[2];
    const float* vfirst = (const float*)d_in[3];
    const float* x_r = (const float*)d_in[4];
    const float* x_w = (const float*)d_in[5];
    const float* x_k = (const float*)d_in[6];
    const float* x_v = (const float*)d_in[7];
    const float* x_a = (const float*)d_in[8];
    const float* x_g = (const float*)d_in[9];
    const float* W_r = (const float*)d_in[10];
    const float* W_k = (const float*)d_in[11];
    const float* W_v = (const float*)d_in[12];
    const float* W_o = (const float*)d_in[13];
    const float* w0 = (const float*)d_in[14];
    const float* w1 = (const float*)d_in[15];
    const float* w2 = (const float*)d_in[16];
    const float* a0 = (const float*)d_in[17];
    const float* a1 = (const float*)d_in[18];
    const float* a2 = (const float*)d_in[19];
    const float* v0 = (const float*)d_in[20];
    const float* v1 = (const float*)d_in[21];
    const float* v2 = (const float*)d_in[22];
    const float* g1 = (const float*)d_in[23];
    const float* g2 = (const float*)d_in[24];
    const float* k_k = (const float*)d_in[25];
    const float* k_a = (const float*)d_in[26];
    const float* r_k = (const float*)d_in[27];
    const float* ln_x_w = (const float*)d_in[28];
    const float* ln_x_b = (const float*)d_in[29];
    const float* ln1_w = (const float*)d_in[30];
    const float* ln1_b = (const float*)d_in[31];

    float* out0 = (float*)d_out;              // (1,T,H)
    float* out1 = out0 + TH;                  // state1_out (H)
    float* out2 = out1 + H_DIM;               // state2_out (NH,HS,HS)
    float* out3 = out2 + NH * HS * HS;        // v_first (1,T,H)

    // workspace layout (fp32 region, then bf16 region) — ~135 MiB total
    float* F = (float*)d_ws;
    float* xn   = F;                          // dead after mix; reused as as_s
    float* as_s = F;
    float* rb   = F + (size_t)1 * TH;
    float* kb   = F + (size_t)2 * TH;         // k -> k_new (in place)
    float* vb   = F + (size_t)3 * TH;         // v -> v_new (in place)
    float* ab   = F + (size_t)4 * TH;         // a -> b_seq (in place)
    float* wpre = F + (size_t)5 * TH;         // wpre -> w decay (in place)
    float* vresb= F + (size_t)6 * TH;
    float* gb   = F + (size_t)7 * TH;
    float* yb   = F + (size_t)8 * TH;
    bf16* B = (bf16*)(F + (size_t)9 * TH);
    bf16 *xrb = B, *xwb = B + (size_t)TH, *xkb = B + (size_t)2 * TH,
         *xvb = B + (size_t)3 * TH, *xab = B + (size_t)4 * TH, *xgb = B + (size_t)5 * TH;
    bf16* Wrb = B + (size_t)6 * TH;
    bf16* Wkb = Wrb + (size_t)HH;
    bf16* Wvb = Wkb + (size_t)HH;
    bf16* Wob = Wvb + (size_t)HH;
    bf16* pp = Wob + (size_t)HH;
    bf16* a1T = pp; pp += (size_t)H_DIM * 64;
    bf16* w1T = pp; pp += (size_t)H_DIM * 64;
    bf16* v1T = pp; pp += (size_t)H_DIM * 32;
    bf16* g1T = pp; pp += (size_t)H_DIM * 128;
    bf16* a2T = pp; pp += (size_t)H_DIM * 64;
    bf16* w2T = pp; pp += (size_t)H_DIM * 64;
    bf16* v2T = pp; pp += (size_t)H_DIM * 32;
    bf16* g2T = pp; pp += (size_t)H_DIM * 128;
    bf16* amid = pp; pp += (size_t)T_TOK * 64;
    bf16* wmid = pp; pp += (size_t)T_TOK * 64;
    bf16* vmid = pp; pp += (size_t)T_TOK * 32;
    bf16* gmid = pp; pp += (size_t)T_TOK * 128;
    bf16* ybig = pp; pp += (size_t)TH;

    // 1. cast big weights to bf16
    CastPar cp;
    cp.src[0] = W_r; cp.src[1] = W_k; cp.src[2] = W_v; cp.src[3] = W_o;
    cp.dst[0] = Wrb; cp.dst[1] = Wkb; cp.dst[2] = Wvb; cp.dst[3] = Wob;
    castw_kernel<<<dim3(HH / 4 / 256, 1, 4), 256, 0, stream>>>(cp);

    // 2. transpose + cast small weights
    TPar tp;
    tp.src[0] = a1; tp.dst[0] = a1T; tp.R[0] = H_DIM; tp.C[0] = 64;
    tp.src[1] = w1; tp.dst[1] = w1T; tp.R[1] = H_DIM; tp.C[1] = 64;
    tp.src[2] = v1; tp.dst[2] = v1T; tp.R[2] = H_DIM; tp.C[2] = 32;
    tp.src[3] = g1; tp.dst[3] = g1T; tp.R[3] = H_DIM; tp.C[3] = 128;
    tp.src[4] = a2; tp.dst[4] = a2T; tp.R[4] = 64;  tp.C[4] = H_DIM;
    tp.src[5] = w2; tp.dst[5] = w2T; tp.R[5] = 64;  tp.C[5] = H_DIM;
    tp.src[6] = v2; tp.dst[6] = v2T; tp.R[6] = 32;  tp.C[6] = H_DIM;
    tp.src[7] = g2; tp.dst[7] = g2T; tp.R[7] = 128; tp.C[7] = H_DIM;
    transpose_kernel<<<dim3((H_DIM * 128 + 255) / 256, 1, 8), 256, 0, stream>>>(tp);

    // 3. LayerNorm -> xn, state1_out
    ln_kernel<<<dim3(T_TOK), 256, 0, stream>>>(x, ln1_w, ln1_b, xn, out1);

    // 4. token-shift mixes -> bf16
    MixPar mp; mp.xn = xn; mp.state1 = state1;
    mp.mv[0] = x_r; mp.mv[1] = x_w; mp.mv[2] = x_k; mp.mv[3] = x_v; mp.mv[4] = x_a; mp.mv[5] = x_g;
    mp.out[0] = xrb; mp.out[1] = xwb; mp.out[2] = xkb; mp.out[3] = xvb; mp.out[4] = xab; mp.out[5] = xgb;
    mix_kernel<<<dim3(T_TOK), 256, 0, stream>>>(mp);

    // 5. r,k,v GEMMs (z-batched)
    GPar gp{}; gp.M = T_TOK;
    gp.X[0] = xrb; gp.W[0] = Wrb; gp.outF[0] = rb; gp.N[0] = H_DIM; gp.K[0] = H_DIM; gp.act[0] = 0;
    gp.X[1] = xkb; gp.W[1] = Wkb; gp.outF[1] = kb; gp.N[1] = H_DIM; gp.K[1] = H_DIM; gp.act[1] = 0;
    gp.X[2] = xvb; gp.W[2] = Wvb; gp.outF[2] = vb; gp.N[2] = H_DIM; gp.K[2] = H_DIM; gp.act[2] = 0;
    gemm_z_kernel<<<dim3(16, 8, 3), 256, 0, stream>>>(gp);

    // 6. low-rank stage 1 (bf16 mids)
    GPar s1{}; s1.M = T_TOK;
    s1.X[0] = xab; s1.W[0] = a1T; s1.outB[0] = amid; s1.N[0] = 64;  s1.K[0] = H_DIM; s1.act[0] = 0;
    s1.X[1] = xwb; s1.W[1] = w1T; s1.outB[1] = wmid; s1.N[1] = 64;  s1.K[1] = H_DIM; s1.act[1] = 2;
    s1.X[2] = xvb; s1.W[2] = v1T; s1.outB[2] = vmid; s1.N[2] = 32;  s1.K[2] = H_DIM; s1.act[2] = 0;
    s1.X[3] = xgb; s1.W[3] = g1T; s1.outB[3] = gmid; s1.N[3] = 128; s1.K[3] = H_DIM; s1.act[3] = 1;
    gemm_z_kernel<<<dim3(1, 8, 4), 256, 0, stream>>>(s1);

    // 7. low-rank stage 2 (fp32 outs)
    GPar s2{}; s2.M = T_TOK;
    s2.X[0] = amid; s2.W[0] = a2T; s2.outF[0] = ab;    s2.N[0] = H_DIM; s2.K[0] = 64;  s2.act[0] = 1; s2.bias[0] = a0;
    s2.X[1] = wmid; s2.W[1] = w2T; s2.outF[1] = wpre;  s2.N[1] = H_DIM; s2.K[1] = 64;  s2.act[1] = 0;
    s2.X[2] = vmid; s2.W[2] = v2T; s2.outF[2] = vresb; s2.N[2] = H_DIM; s2.K[2] = 32;  s2.act[2] = 1; s2.bias[2] = v0;
    s2.X[3] = gmid; s2.W[3] = g2T; s2.outF[3] = gb;    s2.N[3] = H_DIM; s2.K[3] = 128; s2.act[3] = 0;
    gemm_z_kernel<<<dim3(16, 8, 4), 256, 0, stream>>>(s2);

    // 8. elementwise prep (k_new, v_new, w decay, b_seq, a_seq) — in place
    prep_kernel<<<dim3(NH, T_TOK), 64, 0, stream>>>(kb, vb, vfirst, vresb, wpre, ab, as_s, k_k, k_a, w0);

    // 9. sequential scan (one wave per head)
    scan_kernel<<<dim3(NH), 64, 0, stream>>>(wpre, kb, vb, as_s, ab, rb, state2, yb, out2);

    // 10. groupnorm + bonus + gate -> bf16
    post_kernel<<<dim3(NH, T_TOK), 64, 0, stream>>>(yb, rb, kb, vb, gb, r_k, ln_x_w, ln_x_b, ybig);

    // 11. final GEMM with residual add -> out0
    GPar go{}; go.M = T_TOK;
    go.X[0] = ybig; go.W[0] = Wob; go.outF[0] = out0; go.N[0] = H_DIM; go.K[0] = H_DIM; go.act[0] = 0; go.resid[0] = x;
    gemm_z_kernel<<<dim3(16, 8, 1), 256, 0, stream>>>(go);

    // 12. v_first passthrough
    hipMemcpyAsync(out3, (const void*)vfirst, (size_t)TH * sizeof(float),
                   hipMemcpyDeviceToDevice, stream);
}

// Round 2
// 823.740 us; speedup vs baseline: 3.7513x; 3.7513x over previous
//
#include <hip/hip_runtime.h>
#include <hip/hip_bf16.h>
#include <cstdint>
#include <cstddef>

#define T_TOK 1024
#define H_DIM 2048
#define NH 32
#define HS 64
#define TH (T_TOK * H_DIM)
#define HH (H_DIM * H_DIM)

using short8 = __attribute__((ext_vector_type(8))) short;
using f32x4  = __attribute__((ext_vector_type(4))) float;
using f32x8  = __attribute__((ext_vector_type(8))) float;
typedef __hip_bfloat16 bf16;

__device__ __forceinline__ float sigmoidf_(float x) { return 1.0f / (1.0f + expf(-x)); }

__device__ __forceinline__ float wsum64(float v) {
#pragma unroll
    for (int m = 32; m; m >>= 1) v += __shfl_xor(v, m, 64);
    return v;
}

// ---------------- cast big weights fp32 -> bf16 ----------------
struct CastPar { const float* src[4]; bf16* dst[4]; };
__global__ __launch_bounds__(256) void castw_kernel(CastPar p) {
    int z = blockIdx.z;
    const float4* s = (const float4*)p.src[z];
    bf16* d = p.dst[z];
    int i = blockIdx.x * 256 + threadIdx.x;   // float4 index, HH/4 total
    float4 v = s[i];
    int b = i * 4;
    d[b + 0] = __float2bfloat16(v.x);
    d[b + 1] = __float2bfloat16(v.y);
    d[b + 2] = __float2bfloat16(v.z);
    d[b + 3] = __float2bfloat16(v.w);
}

// ---------------- transpose + cast small weights ----------------
struct TPar { const float* src[8]; bf16* dst[8]; int R[8]; int C[8]; };
__global__ __launch_bounds__(256) void transpose_kernel(TPar p) {
    int z = blockIdx.z;
    int R = p.R[z], C = p.C[z];
    int e = blockIdx.x * 256 + threadIdx.x;
    if (e >= R * C) return;
    int r = e / C, c = e % C;
    p.dst[z][(size_t)c * R + r] = __float2bfloat16(p.src[z][e]);
}

// ---------------- LayerNorm (ln1) over H, write xn + state1_out ----------------
__global__ __launch_bounds__(256) void ln_kernel(const float* __restrict__ x,
                                                 const float* __restrict__ w,
                                                 const float* __restrict__ b,
                                                 float* __restrict__ xn,
                                                 float* __restrict__ s1out) {
    int t = blockIdx.x, tid = threadIdx.x;
    const float* xt = x + (size_t)t * H_DIM;
    float v[8]; float s = 0.f, s2 = 0.f;
#pragma unroll
    for (int e = 0; e < 8; e++) { v[e] = xt[tid + 256 * e]; s += v[e]; s2 += v[e] * v[e]; }
    s = wsum64(s); s2 = wsum64(s2);
    __shared__ float ls[8];
    int wid = tid >> 6, ln = tid & 63;
    if (ln == 0) { ls[wid] = s; ls[4 + wid] = s2; }
    __syncthreads();
    s = ls[0] + ls[1] + ls[2] + ls[3];
    s2 = ls[4] + ls[5] + ls[6] + ls[7];
    float mu = s * (1.f / H_DIM);
    float var = s2 * (1.f / H_DIM) - mu * mu;
    float inv = rsqrtf(var + 1e-5f);
#pragma unroll
    for (int e = 0; e < 8; e++) {
        int h = tid + 256 * e;
        float o = (v[e] - mu) * inv * w[h] + b[h];
        xn[(size_t)t * H_DIM + h] = o;
        if (t == T_TOK - 1) s1out[h] = o;
    }
}

// ---------------- token-shift mixes -> 6 bf16 buffers ----------------
struct MixPar { const float* xn; const float* state1; const float* mv[6]; bf16* out[6]; };
__global__ __launch_bounds__(256) void mix_kernel(MixPar p) {
    int t = blockIdx.x, tid = threadIdx.x;
#pragma unroll
    for (int e = 0; e < 8; e++) {
        int h = tid + 256 * e;
        size_t idx = (size_t)t * H_DIM + h;
        float cur = p.xn[idx];
        float prev = (t == 0) ? p.state1[h] : p.xn[idx - H_DIM];
        float sx = prev - cur;
#pragma unroll
        for (int q = 0; q < 6; q++)
            p.out[q][idx] = __float2bfloat16(cur + p.mv[q][h] * sx);
    }
}

// ---------------- MFMA bf16 GEMM: C[M,N] = X[M,K] @ W[N,K]^T ----------------
#define BM 128
#define BN 128
#define BK 32
#define LDK 40   // +8 bf16 pad to break power-of-2 bank stride

__device__ __forceinline__ void gemm_core(const bf16* __restrict__ X, const bf16* __restrict__ W,
                                          int M, int N, int K, int act,
                                          const float* __restrict__ bias,
                                          const float* __restrict__ resid,
                                          float* __restrict__ outF, bf16* __restrict__ outB) {
    __shared__ short As[BM * LDK];
    __shared__ short Bs[BN * LDK];
    int m0 = blockIdx.y * BM, n0 = blockIdx.x * BN;
    if (n0 >= N) return;
    int tid = threadIdx.x;
    int lane = tid & 63, wid = tid >> 6;
    int m_off = (wid >> 1) * 64, n_off = (wid & 1) * 64;
    int lr = lane & 15, lq = lane >> 4;

    f32x4 acc[4][4];
#pragma unroll
    for (int a = 0; a < 4; a++)
#pragma unroll
        for (int b = 0; b < 4; b++)
#pragma unroll
            for (int r = 0; r < 4; r++) acc[a][b][r] = 0.f;

    for (int k0 = 0; k0 < K; k0 += BK) {
#pragma unroll
        for (int it = 0; it < 2; it++) {
            int c = tid + it * 256;
            int r = c >> 2;
            int cc = (c & 3) * 8;
            uint4 va = *(const uint4*)(X + (size_t)(m0 + r) * K + k0 + cc);
            *(uint4*)&As[r * LDK + cc] = va;
            uint4 vb;
            if (n0 + r < N) vb = *(const uint4*)(W + (size_t)(n0 + r) * K + k0 + cc);
            else            vb = make_uint4(0u, 0u, 0u, 0u);
            *(uint4*)&Bs[r * LDK + cc] = vb;
        }
        __syncthreads();
        short8 af[4], bfr[4];
#pragma unroll
        for (int mi = 0; mi < 4; mi++)
            af[mi] = *(const short8*)&As[(m_off + mi * 16 + lr) * LDK + lq * 8];
#pragma unroll
        for (int ni = 0; ni < 4; ni++)
            bfr[ni] = *(const short8*)&Bs[(n_off + ni * 16 + lr) * LDK + lq * 8];
#pragma unroll
        for (int mi = 0; mi < 4; mi++)
#pragma unroll
            for (int ni = 0; ni < 4; ni++)
                acc[mi][ni] = __builtin_amdgcn_mfma_f32_16x16x32_bf16(af[mi], bfr[ni], acc[mi][ni], 0, 0, 0);
        __syncthreads();
    }
    // epilogue: D row = quad*4+reg, col = lane&15  (m89-verified layout)
#pragma unroll
    for (int mi = 0; mi < 4; mi++)
#pragma unroll
        for (int ni = 0; ni < 4; ni++)
#pragma unroll
            for (int r = 0; r < 4; r++) {
                int rowg = m0 + m_off + mi * 16 + lq * 4 + r;
                int colg = n0 + n_off + ni * 16 + lr;
                if (colg < N) {
                    float v = acc[mi][ni][r];
                    if (bias) v += bias[colg];
                    if (act == 1) v = sigmoidf_(v);
                    else if (act == 2) v = tanhf(v);
                    size_t o = (size_t)rowg * N + colg;
                    if (resid) v += resid[o];
                    if (outF) outF[o] = v;
                    else      outB[o] = __float2bfloat16(v);
                }
            }
}

struct GPar {
    const bf16* X[4]; const bf16* W[4];
    float* outF[4]; bf16* outB[4];
    const float* bias[4]; const float* resid[4];
    int N[4]; int K[4]; int act[4]; int M;
};
__global__ __launch_bounds__(256) void gemm_z_kernel(GPar p) {
    int z = blockIdx.z;
    gemm_core(p.X[z], p.W[z], p.M, p.N[z], p.K[z], p.act[z], p.bias[z], p.resid[z], p.outF[z], p.outB[z]);
}

// ---------------- elementwise prep for the scan ----------------
__global__ __launch_bounds__(64) void prep_kernel(float* __restrict__ k_io, float* __restrict__ v_io,
                                                  const float* __restrict__ v_first,
                                                  const float* __restrict__ vres,
                                                  float* __restrict__ w_io, float* __restrict__ a_io,
                                                  float* __restrict__ as_out,
                                                  const float* __restrict__ k_k,
                                                  const float* __restrict__ k_a,
                                                  const float* __restrict__ w0) {
    int h = blockIdx.x, t = blockIdx.y, i = threadIdx.x;
    int hi = h * HS + i;
    size_t idx = (size_t)t * H_DIM + hi;
    float kf = k_io[idx];
    float kk = kf * k_k[hi];
    float ss = wsum64(kk * kk);
    float kkn = kk / (sqrtf(ss) + 1e-12f);
    float a = a_io[idx];
    k_io[idx] = kf * (1.f + (a - 1.f) * k_a[hi]);
    float vv = v_io[idx];
    v_io[idx] = vv + (v_first[idx] - vv) * vres[idx];
    w_io[idx] = expf(-0.606531f * sigmoidf_(w0[hi] + w_io[idx]));
    a_io[idx] = kkn * a;     // b_seq
    as_out[idx] = -kkn;      // a_seq
}

// ---------------- sequential WKV7 scan: 8 waves per head ----------------
// Head state S[64][64] split into 8 row-groups of 8 rows. Wave (h,q) owns
// rows q*8..q*8+7. Lane il*8+jb holds S[q*8+il][jb*8 .. jb*8+8) in VGPRs.
// j-reductions = 3 shfl_xor over low lane bits. Per-step vectors are
// per-lane float4 loads, software-pipelined 2 steps ahead (4x unroll so
// register roles rotate without v_mov copies).
#define NSPLIT 8
#define RPW (HS / NSPLIT)

struct StepV { f32x8 w, a, b, k, r; float v; };

__device__ __forceinline__ f32x8 ld8(const float* __restrict__ p) {
    float4 lo = *(const float4*)p;
    float4 hi = *(const float4*)(p + 4);
    f32x8 r;
    r[0] = lo.x; r[1] = lo.y; r[2] = lo.z; r[3] = lo.w;
    r[4] = hi.x; r[5] = hi.y; r[6] = hi.z; r[7] = hi.w;
    return r;
}

__device__ __forceinline__ StepV ldstep(const float* __restrict__ w_s,
                                        const float* __restrict__ as_s,
                                        const float* __restrict__ b_s,
                                        const float* __restrict__ k_s,
                                        const float* __restrict__ v_s,
                                        const float* __restrict__ r_s,
                                        int t, int hb, int jo, int row) {
    size_t tb = (size_t)t * H_DIM + hb;
    StepV s;
    s.w = ld8(w_s + tb + jo);
    s.a = ld8(as_s + tb + jo);
    s.b = ld8(b_s + tb + jo);
    s.k = ld8(k_s + tb + jo);
    s.r = ld8(r_s + tb + jo);
    s.v = v_s[tb + row];
    return s;
}

__device__ __forceinline__ void step_compute(float S[8], const StepV& sv,
                                             float* __restrict__ y,
                                             int t, int hb, int row, int jb) {
    float sa = 0.f;
#pragma unroll
    for (int e = 0; e < 8; e++) { S[e] *= sv.w[e]; sa = fmaf(S[e], sv.a[e], sa); }
    sa += __shfl_xor(sa, 1, 64);
    sa += __shfl_xor(sa, 2, 64);
    sa += __shfl_xor(sa, 4, 64);
    float o = 0.f;
#pragma unroll
    for (int e = 0; e < 8; e++) {
        S[e] = fmaf(sa, sv.b[e], fmaf(sv.v, sv.k[e], S[e]));
        o = fmaf(S[e], sv.r[e], o);
    }
    o += __shfl_xor(o, 1, 64);
    o += __shfl_xor(o, 2, 64);
    o += __shfl_xor(o, 4, 64);
    if (jb == 0) y[(size_t)t * H_DIM + hb + row] = o;
}

__global__ __launch_bounds__(64) void scan_kernel(const float* __restrict__ w_s,
                                                  const float* __restrict__ k_s,
                                                  const float* __restrict__ v_s,
                                                  const float* __restrict__ as_s,
                                                  const float* __restrict__ b_s,
                                                  const float* __restrict__ r_s,
                                                  const float* __restrict__ s2in,
                                                  float* __restrict__ y,
                                                  float* __restrict__ s2out) {
    int h = blockIdx.x, q = blockIdx.y;
    int lane = threadIdx.x;
    int il = lane >> 3, jb = lane & 7;
    int row = q * RPW + il;
    int jo = jb * 8;
    int hb = h * HS;

    float S[8];
    {
        const float* s0 = s2in + (size_t)h * HS * HS + (size_t)row * HS + jo;
        float4 t0 = *(const float4*)s0, t1 = *(const float4*)(s0 + 4);
        S[0] = t0.x; S[1] = t0.y; S[2] = t0.z; S[3] = t0.w;
        S[4] = t1.x; S[5] = t1.y; S[6] = t1.z; S[7] = t1.w;
    }

#define LDS_(tt) ldstep(w_s, as_s, b_s, k_s, v_s, r_s, ((tt) < T_TOK ? (tt) : T_TOK - 1), hb, jo, row)
    StepV c0 = LDS_(0);
    StepV c1 = LDS_(1);
    for (int t = 0; t < T_TOK; t += 4) {
        StepV n0 = LDS_(t + 2); step_compute(S, c0, y, t,     hb, row, jb);
        StepV n1 = LDS_(t + 3); step_compute(S, c1, y, t + 1, hb, row, jb);
        c0 = LDS_(t + 4);       step_compute(S, n0, y, t + 2, hb, row, jb);
        c1 = LDS_(t + 5);       step_compute(S, n1, y, t + 3, hb, row, jb);
    }
#undef LDS_

    {
        float* so = s2out + (size_t)h * HS * HS + (size_t)row * HS + jo;
        float4 t0, t1;
        t0.x = S[0]; t0.y = S[1]; t0.z = S[2]; t0.w = S[3];
        t1.x = S[4]; t1.y = S[5]; t1.z = S[6]; t1.w = S[7];
        *(float4*)so = t0; *(float4*)(so + 4) = t1;
    }
}

// ---------------- groupnorm + bonus + gate -> bf16 for final GEMM ----------------
__global__ __launch_bounds__(64) void post_kernel(const float* __restrict__ y,
                                                  const float* __restrict__ r_s,
                                                  const float* __restrict__ k_s,
                                                  const float* __restrict__ v_s,
                                                  const float* __restrict__ g_s,
                                                  const float* __restrict__ r_k,
                                                  const float* __restrict__ lnw,
                                                  const float* __restrict__ lnb,
                                                  bf16* __restrict__ ybig) {
    int h = blockIdx.x, t = blockIdx.y, i = threadIdx.x;
    int hi = h * HS + i;
    size_t idx = (size_t)t * H_DIM + hi;
    float yv = y[idx];
    float mu = wsum64(yv) * (1.f / HS);
    float d = yv - mu;
    float var = wsum64(d * d) * (1.f / HS);
    float yn = d * rsqrtf(var + 0.00064f);
    float bd = wsum64(r_s[idx] * k_s[idx] * r_k[hi]);
    float val = (yn * lnw[hi] + lnb[hi] + bd * v_s[idx]) * g_s[idx];
    ybig[idx] = __float2bfloat16(val);
}

// ---------------- launcher ----------------
extern "C" void kernel_launch(void* const* d_in, const int* in_sizes, int n_in,
                              void* d_out, int out_size, void* d_ws, size_t ws_size,
                              hipStream_t stream) {
    const float* x      = (const float*)d_in[0];
    const float* state1 = (const float*)d_in[1];
    const float* state2 = (const float*)d_in[2];
    const float* vfirst = (const float*)d_in[3];
    const float* x_r = (const float*)d_in[4];
    const float* x_w = (const float*)d_in[5];
    const float* x_k = (const float*)d_in[6];
    const float* x_v = (const float*)d_in[7];
    const float* x_a = (const float*)d_in[8];
    const float* x_g = (const float*)d_in[9];
    const float* W_r = (const float*)d_in[10];
    const float* W_k = (const float*)d_in[11];
    const float* W_v = (const float*)d_in[12];
    const float* W_o = (const float*)d_in[13];
    const float* w0 = (const float*)d_in[14];
    const float* w1 = (const float*)d_in[15];
    const float* w2 = (const float*)d_in[16];
    const float* a0 = (const float*)d_in[17];
    const float* a1 = (const float*)d_in[18];
    const float* a2 = (const float*)d_in[19];
    const float* v0 = (const float*)d_in[20];
    const float* v1 = (const float*)d_in[21];
    const float* v2 = (const float*)d_in[22];
    const float* g1 = (const float*)d_in[23];
    const float* g2 = (const float*)d_in[24];
    const float* k_k = (const float*)d_in[25];
    const float* k_a = (const float*)d_in[26];
    const float* r_k = (const float*)d_in[27];
    const float* ln_x_w = (const float*)d_in[28];
    const float* ln_x_b = (const float*)d_in[29];
    const float* ln1_w = (const float*)d_in[30];
    const float* ln1_b = (const float*)d_in[31];

    float* out0 = (float*)d_out;              // (1,T,H)
    float* out1 = out0 + TH;                  // state1_out (H)
    float* out2 = out1 + H_DIM;               // state2_out (NH,HS,HS)
    float* out3 = out2 + NH * HS * HS;        // v_first (1,T,H)

    // workspace layout (fp32 region, then bf16 region) — ~135 MiB total
    float* F = (float*)d_ws;
    float* xn   = F;                          // dead after mix; reused as as_s
    float* as_s = F;
    float* rb   = F + (size_t)1 * TH;
    float* kb   = F + (size_t)2 * TH;         // k -> k_new (in place)
    float* vb   = F + (size_t)3 * TH;         // v -> v_new (in place)
    float* ab   = F + (size_t)4 * TH;         // a -> b_seq (in place)
    float* wpre = F + (size_t)5 * TH;         // wpre -> w decay (in place)
    float* vresb= F + (size_t)6 * TH;
    float* gb   = F + (size_t)7 * TH;
    float* yb   = F + (size_t)8 * TH;
    bf16* B = (bf16*)(F + (size_t)9 * TH);
    bf16 *xrb = B, *xwb = B + (size_t)TH, *xkb = B + (size_t)2 * TH,
         *xvb = B + (size_t)3 * TH, *xab = B + (size_t)4 * TH, *xgb = B + (size_t)5 * TH;
    bf16* Wrb = B + (size_t)6 * TH;
    bf16* Wkb = Wrb + (size_t)HH;
    bf16* Wvb = Wkb + (size_t)HH;
    bf16* Wob = Wvb + (size_t)HH;
    bf16* pp = Wob + (size_t)HH;
    bf16* a1T = pp; pp += (size_t)H_DIM * 64;
    bf16* w1T = pp; pp += (size_t)H_DIM * 64;
    bf16* v1T = pp; pp += (size_t)H_DIM * 32;
    bf16* g1T = pp; pp += (size_t)H_DIM * 128;
    bf16* a2T = pp; pp += (size_t)H_DIM * 64;
    bf16* w2T = pp; pp += (size_t)H_DIM * 64;
    bf16* v2T = pp; pp += (size_t)H_DIM * 32;
    bf16* g2T = pp; pp += (size_t)H_DIM * 128;
    bf16* amid = pp; pp += (size_t)T_TOK * 64;
    bf16* wmid = pp; pp += (size_t)T_TOK * 64;
    bf16* vmid = pp; pp += (size_t)T_TOK * 32;
    bf16* gmid = pp; pp += (size_t)T_TOK * 128;
    bf16* ybig = pp; pp += (size_t)TH;

    // 1. cast big weights to bf16
    CastPar cp;
    cp.src[0] = W_r; cp.src[1] = W_k; cp.src[2] = W_v; cp.src[3] = W_o;
    cp.dst[0] = Wrb; cp.dst[1] = Wkb; cp.dst[2] = Wvb; cp.dst[3] = Wob;
    castw_kernel<<<dim3(HH / 4 / 256, 1, 4), 256, 0, stream>>>(cp);

    // 2. transpose + cast small weights
    TPar tp;
    tp.src[0] = a1; tp.dst[0] = a1T; tp.R[0] = H_DIM; tp.C[0] = 64;
    tp.src[1] = w1; tp.dst[1] = w1T; tp.R[1] = H_DIM; tp.C[1] = 64;
    tp.src[2] = v1; tp.dst[2] = v1T; tp.R[2] = H_DIM; tp.C[2] = 32;
    tp.src[3] = g1; tp.dst[3] = g1T; tp.R[3] = H_DIM; tp.C[3] = 128;
    tp.src[4] = a2; tp.dst[4] = a2T; tp.R[4] = 64;  tp.C[4] = H_DIM;
    tp.src[5] = w2; tp.dst[5] = w2T; tp.R[5] = 64;  tp.C[5] = H_DIM;
    tp.src[6] = v2; tp.dst[6] = v2T; tp.R[6] = 32;  tp.C[6] = H_DIM;
    tp.src[7] = g2; tp.dst[7] = g2T; tp.R[7] = 128; tp.C[7] = H_DIM;
    transpose_kernel<<<dim3((H_DIM * 128 + 255) / 256, 1, 8), 256, 0, stream>>>(tp);

    // 3. LayerNorm -> xn, state1_out
    ln_kernel<<<dim3(T_TOK), 256, 0, stream>>>(x, ln1_w, ln1_b, xn, out1);

    // 4. token-shift mixes -> bf16
    MixPar mp; mp.xn = xn; mp.state1 = state1;
    mp.mv[0] = x_r; mp.mv[1] = x_w; mp.mv[2] = x_k; mp.mv[3] = x_v; mp.mv[4] = x_a; mp.mv[5] = x_g;
    mp.out[0] = xrb; mp.out[1] = xwb; mp.out[2] = xkb; mp.out[3] = xvb; mp.out[4] = xab; mp.out[5] = xgb;
    mix_kernel<<<dim3(T_TOK), 256, 0, stream>>>(mp);

    // 5. r,k,v GEMMs (z-batched)
    GPar gp{}; gp.M = T_TOK;
    gp.X[0] = xrb; gp.W[0] = Wrb; gp.outF[0] = rb; gp.N[0] = H_DIM; gp.K[0] = H_DIM; gp.act[0] = 0;
    gp.X[1] = xkb; gp.W[1] = Wkb; gp.outF[1] = kb; gp.N[1] = H_DIM; gp.K[1] = H_DIM; gp.act[1] = 0;
    gp.X[2] = xvb; gp.W[2] = Wvb; gp.outF[2] = vb; gp.N[2] = H_DIM; gp.K[2] = H_DIM; gp.act[2] = 0;
    gemm_z_kernel<<<dim3(16, 8, 3), 256, 0, stream>>>(gp);

    // 6. low-rank stage 1 (bf16 mids)
    GPar s1{}; s1.M = T_TOK;
    s1.X[0] = xab; s1.W[0] = a1T; s1.outB[0] = amid; s1.N[0] = 64;  s1.K[0] = H_DIM; s1.act[0] = 0;
    s1.X[1] = xwb; s1.W[1] = w1T; s1.outB[1] = wmid; s1.N[1] = 64;  s1.K[1] = H_DIM; s1.act[1] = 2;
    s1.X[2] = xvb; s1.W[2] = v1T; s1.outB[2] = vmid; s1.N[2] = 32;  s1.K[2] = H_DIM; s1.act[2] = 0;
    s1.X[3] = xgb; s1.W[3] = g1T; s1.outB[3] = gmid; s1.N[3] = 128; s1.K[3] = H_DIM; s1.act[3] = 1;
    gemm_z_kernel<<<dim3(1, 8, 4), 256, 0, stream>>>(s1);

    // 7. low-rank stage 2 (fp32 outs)
    GPar s2{}; s2.M = T_TOK;
    s2.X[0] = amid; s2.W[0] = a2T; s2.outF[0] = ab;    s2.N[0] = H_DIM; s2.K[0] = 64;  s2.act[0] = 1; s2.bias[0] = a0;
    s2.X[1] = wmid; s2.W[1] = w2T; s2.outF[1] = wpre;  s2.N[1] = H_DIM; s2.K[1] = 64;  s2.act[1] = 0;
    s2.X[2] = vmid; s2.W[2] = v2T; s2.outF[2] = vresb; s2.N[2] = H_DIM; s2.K[2] = 32;  s2.act[2] = 1; s2.bias[2] = v0;
    s2.X[3] = gmid; s2.W[3] = g2T; s2.outF[3] = gb;    s2.N[3] = H_DIM; s2.K[3] = 128; s2.act[3] = 0;
    gemm_z_kernel<<<dim3(16, 8, 4), 256, 0, stream>>>(s2);

    // 8. elementwise prep (k_new, v_new, w decay, b_seq, a_seq) — in place
    prep_kernel<<<dim3(NH, T_TOK), 64, 0, stream>>>(kb, vb, vfirst, vresb, wpre, ab, as_s, k_k, k_a, w0);

    // 9. sequential scan (8 waves per head, 256 workgroups)
    scan_kernel<<<dim3(NH, NSPLIT), 64, 0, stream>>>(wpre, kb, vb, as_s, ab, rb, state2, yb, out2);

    // 10. groupnorm + bonus + gate -> bf16
    post_kernel<<<dim3(NH, T_TOK), 64, 0, stream>>>(yb, rb, kb, vb, gb, r_k, ln_x_w, ln_x_b, ybig);

    // 11. final GEMM with residual add -> out0
    GPar go{}; go.M = T_TOK;
    go.X[0] = ybig; go.W[0] = Wob; go.outF[0] = out0; go.N[0] = H_DIM; go.K[0] = H_DIM; go.act[0] = 0; go.resid[0] = x;
    gemm_z_kernel<<<dim3(16, 8, 1), 256, 0, stream>>>(go);

    // 12. v_first passthrough
    hipMemcpyAsync(out3, (const void*)vfirst, (size_t)TH * sizeof(float),
                   hipMemcpyDeviceToDevice, stream);
}